// Round 15
// baseline (332.472 us; speedup 1.0000x reference)
//
#include <hip/hip_runtime.h>
#include <hip/hip_bf16.h>

typedef __bf16 bf16_t;
typedef __bf16 bf16x4 __attribute__((ext_vector_type(4)));
typedef __bf16 bf16x8 __attribute__((ext_vector_type(8)));
typedef float  f32x4  __attribute__((ext_vector_type(4)));

#define HEPS 1e-6f

__device__ __forceinline__ void gload16(const bf16_t* g, bf16_t* l) {
    __builtin_amdgcn_global_load_lds(
        (const __attribute__((address_space(1))) unsigned int*)(g),
        (__attribute__((address_space(3))) unsigned int*)(l),
        16, 0, 0);
}

// ---------------- setup: weight cvt + Dinit transpose + BN folding, one launch ----------
__global__ void setup_k(const float* __restrict__ wl, bf16_t* __restrict__ dwl,
                        const float* __restrict__ wc, bf16_t* __restrict__ dwc,
                        const float* __restrict__ wu, bf16_t* __restrict__ dwu,
                        const float* __restrict__ Ds, const float* __restrict__ Dc,
                        bf16_t* __restrict__ Dt,
                        const float* __restrict__ chg, const float* __restrict__ chb,
                        const float* __restrict__ chm, const float* __restrict__ chv,
                        const float* __restrict__ hg, const float* __restrict__ hb,
                        const float* __restrict__ hm, const float* __restrict__ hv,
                        const float* __restrict__ ub, const float* __restrict__ cham,
                        float* __restrict__ chA, float* __restrict__ chB,
                        float* __restrict__ hA2, float* __restrict__ hB2) {
    int bid = blockIdx.x;
    int tid = threadIdx.x;
    if (bid < 8192) {
        int i = bid * 256 + tid;
        if (i < 524288) dwl[i] = (bf16_t)wl[i];
        else if (i < 1572864) { int k = i - 524288; dwc[k] = (bf16_t)wc[k]; }
        else { int k = i - 1572864; dwu[k] = (bf16_t)wu[k]; }
    } else if (bid < 10240) {
        int b2 = bid - 8192;
        int bs = b2 >> 7;
        int idx = (b2 & 127) * 256 + tid;
        int b = bs >> 1;
        const float* src = ((bs & 1) ? Dc : Ds) + (size_t)b * 512 * 64;
        int r = idx & 63, d = idx >> 6;
        Dt[(size_t)bs * 64 * 512 + (size_t)r * 512 + d] = (bf16_t)src[d * 64 + r];
    } else {
        int i = (bid - 10240) * 256 + tid;
        if (i < 1024) {
            float inv = chg[i] * rsqrtf(chv[i] + 1e-5f);
            chA[i] = inv;
            chB[i] = chb[i] - chm[i] * inv;
        }
        if (i < 512) {
            float inv = hg[i] * rsqrtf(hv[i] + 1e-5f);
            float cA = cham[0];
            hA2[i] = cA * inv;
            hB2[i] = cA * (fmaf(ub[i], inv, hb[i]) - hm[i] * inv);
        }
    }
}

// z [b][512][4096] fp32 -> Zt [b][4096][512] bf16, plus zb = bf16 copy of z
__global__ void tz_k(const float* __restrict__ z, bf16_t* __restrict__ Zt,
                     bf16_t* __restrict__ zb) {
    __shared__ bf16_t t[64][68];
    int b = blockIdx.z, kt = blockIdx.y, nt = blockIdx.x;
    const size_t boff = ((size_t)b * 512 + kt * 64) * 4096 + nt * 64;
    const float* src = z + boff;
    bf16_t* zbo = zb + boff;
    int tid = threadIdx.x;
    int kr = tid >> 4;
    int nc = (tid & 15) * 4;
    #pragma unroll
    for (int it = 0; it < 4; ++it) {
        int k = kr + it * 16;
        float4 v = *(const float4*)&src[(size_t)k * 4096 + nc];
        bf16x4 o;
        o[0] = (bf16_t)v.x; o[1] = (bf16_t)v.y; o[2] = (bf16_t)v.z; o[3] = (bf16_t)v.w;
        t[nc + 0][k] = o[0]; t[nc + 1][k] = o[1];
        t[nc + 2][k] = o[2]; t[nc + 3][k] = o[3];
        *(bf16x4*)&zbo[(size_t)k * 4096 + nc] = o;
    }
    __syncthreads();
    bf16_t* dst = Zt + ((size_t)b * 4096 + nt * 64) * 512 + kt * 64;
    int nr = tid >> 4;
    int kc = (tid & 15) * 4;
    #pragma unroll
    for (int it = 0; it < 4; ++it) {
        int n = nr + it * 16;
        bf16x4 o;
        #pragma unroll
        for (int c = 0; c < 4; ++c) o[c] = t[n][kc + c];
        *(bf16x4*)&dst[(size_t)n * 512 + kc] = o;
    }
}

// Xt [b][4096][1024] -> X [b][1024][4096]  (64x64 LDS tiles, both sides 16B)
__global__ void xp_k(const bf16_t* __restrict__ Xt, bf16_t* __restrict__ X) {
    __shared__ bf16_t t[64][72];
    int b = blockIdx.z, dt = blockIdx.y, nt = blockIdx.x;
    const bf16_t* src = Xt + ((size_t)b * 4096 + nt * 64) * 1024 + dt * 64;
    int tid = threadIdx.x;
    int r = tid >> 2, c = (tid & 3) * 16;
    #pragma unroll
    for (int u = 0; u < 2; ++u) {
        bf16x8 v = *(const bf16x8*)&src[(size_t)r * 1024 + c + u * 8];
        *(bf16x8*)&t[r][c + u * 8] = v;
    }
    __syncthreads();
    bf16_t* dst = X + ((size_t)b * 1024 + dt * 64) * 4096 + nt * 64;
    #pragma unroll
    for (int u = 0; u < 2; ++u) {
        int dr = r;                        // do row within tile
        int ncol = c + u * 8;              // n col base
        bf16x8 o;
        #pragma unroll
        for (int e = 0; e < 8; ++e) o[e] = t[ncol + e][dr];
        *(bf16x8*)&dst[(size_t)dr * 4096 + ncol] = o;
    }
}

__global__ void dnorm_k(const bf16_t* __restrict__ Dt, float* __restrict__ dinv) {
    int gw = (blockIdx.x * 256 + threadIdx.x) >> 6;
    int lane = threadIdx.x & 63;
    bf16x8 v = *(const bf16x8*)(Dt + (size_t)gw * 512 + lane * 8);
    float s = 0.f;
    #pragma unroll
    for (int e = 0; e < 8; ++e) { float f = (float)v[e]; s += f * f; }
    #pragma unroll
    for (int off = 32; off > 0; off >>= 1) s += __shfl_xor(s, off);
    if (lane == 0) dinv[gw] = 1.0f / fmaxf(sqrtf(s), HEPS);
}

// sum 8 split-K partials P[bs*8+kc][r][d] -> Dt bf16, plus dinv of summed rows
__global__ void reduce_k(const float* __restrict__ P, bf16_t* __restrict__ Dt,
                         float* __restrict__ dinv) {
    int bsr = blockIdx.x;
    int bs = bsr >> 6, r = bsr & 63;
    int lane = threadIdx.x;
    const float* base = P + ((size_t)(bs * 8) * 64 + r) * 512 + lane * 8;
    float s[8] = {0.f, 0.f, 0.f, 0.f, 0.f, 0.f, 0.f, 0.f};
    #pragma unroll
    for (int kc = 0; kc < 8; ++kc) {
        const float* p = base + (size_t)kc * 64 * 512;
        float4 u = *(const float4*)p;
        float4 w = *(const float4*)(p + 4);
        s[0] += u.x; s[1] += u.y; s[2] += u.z; s[3] += u.w;
        s[4] += w.x; s[5] += w.y; s[6] += w.z; s[7] += w.w;
    }
    bf16x8 o;
    float sq = 0.f;
    #pragma unroll
    for (int e = 0; e < 8; ++e) { sq += s[e] * s[e]; o[e] = (bf16_t)s[e]; }
    *(bf16x8*)&Dt[(size_t)bsr * 512 + lane * 8] = o;
    #pragma unroll
    for (int off = 32; off > 0; off >>= 1) sq += __shfl_xor(sq, off);
    if (lane == 0) dinv[bsr] = 1.0f / fmaxf(sqrtf(sq), HEPS);
}

// ---------------- MFMA GEMM: 3-buffer, counted vmcnt, SINGLE barrier per K-step --------
// EPI 2: cheese' (col a*x+b, relu, bf16)
// EPI 3: upper (row a*x+b + cB*bf16-shortcut via LDS-bounced tile, relu, fp32)
// EPI 5: XCt split-K=8 partial (transposed fp32)
// EPI 6: S^T + fused row softmax (WAVES_N must be 1)
// EPI 7: E (scale col by dinv, concat store)
// EPI 9: G1'' (row bias + relu, transposed bf16x4 store -> Xt only)
template<int BM, int BN, int WAVES_M, int WAVES_N, int EPI, int ORDER>
__launch_bounds__(256)
__global__ void g2(const bf16_t* __restrict__ Ag, const bf16_t* __restrict__ Bg,
                   void* __restrict__ Cg, void* __restrict__ C2g,
                   const int M, const int N, const int K,
                   const int ldA, const int ldB, const int ldC,
                   const long aStride, const long bStride,
                   const long cStride, const long c2Stride,
                   const float* __restrict__ p0, const float* __restrict__ p1,
                   const float* __restrict__ scal,
                   const void* __restrict__ shortcut, const long sStride)
{
    constexpr int WM = BM / WAVES_M, WN = BN / WAVES_N;
    constexpr int FM = WM / 16, FN = WN / 16;
    constexpr int ASEG = BM / 64, BSEG = BN / 64;
    constexpr int LPT = ASEG + BSEG;

    __shared__ __align__(64) bf16_t SH[3 * (BM + BN) * 32];
    __shared__ float dl[64];
    bf16_t* Al = SH;
    bf16_t* Bl = SH + 3 * BM * 32;

    const int tid = threadIdx.x;
    const int wave = tid >> 6, lane = tid & 63;
    const int l15 = lane & 15, q = lane >> 4;
    const int lrow = lane >> 2, lcol = (lane & 3) * 8;

    // ---- XCD-chunked bijective remap (m204) ----
    const int gx = gridDim.x, gy = gridDim.y;
    const int per = gx * gy;
    const int nwg = per * gridDim.z;
    const int g = blockIdx.z * per + blockIdx.y * gx + blockIdx.x;
    const int qq = nwg >> 3, rr = nwg & 7;
    const int xcd = g & 7, jj = g >> 3;
    const int w = (xcd < rr ? xcd * (qq + 1) : rr * (qq + 1) + (xcd - rr) * qq) + jj;
    const int bz = w / per;
    const int rem = w - bz * per;
    int bx, by;
    if constexpr (ORDER == 0) { by = rem / gx; bx = rem - by * gx; }
    else                      { bx = rem / gy; by = rem - bx * gy; }

    int bs = bz, exA = 0, exB = 0;
    if constexpr (EPI == 5) { bs = bz >> 3; exA = exB = (bz & 7) * 512; }
    if constexpr (EPI == 7) { exA = (bz & 1) * 512; }

    const int n0 = bx * BN;
    const int m0 = by * BM;
    const int wm0 = (wave / WAVES_N) * WM;
    const int wn0 = (wave % WAVES_N) * WN;

    const bf16_t* Ab;
    const bf16_t* Bb;
    if constexpr (EPI == 6) {
        Ab = Ag + (size_t)(bz >> 1) * (size_t)aStride + (size_t)(bz & 1) * 512;
        Bb = Bg + (size_t)bz * (size_t)bStride;
    } else {
        Ab = Ag + (size_t)bs * (size_t)aStride + exA;
        Bb = Bg + (size_t)bs * (size_t)bStride + exB;
    }

    if constexpr (EPI == 6) { if (tid < 64) dl[tid] = p0[bz * 64 + tid]; }

    auto stage = [&](int buf, int k0) {
        #pragma unroll
        for (int t = 0; t < ASEG; ++t) {
            int seg = wave * ASEG + t;
            gload16(Ab + (size_t)(m0 + seg * 16 + lrow) * ldA + k0 + lcol,
                    &Al[buf * BM * 32 + seg * 512]);
        }
        #pragma unroll
        for (int t = 0; t < BSEG; ++t) {
            int seg = wave * BSEG + t;
            gload16(Bb + (size_t)(n0 + seg * 16 + lrow) * ldB + k0 + lcol,
                    &Bl[buf * BN * 32 + seg * 512]);
        }
    };

    f32x4 acc[FM][FN];
    #pragma unroll
    for (int i = 0; i < FM; ++i)
        #pragma unroll
        for (int j = 0; j < FN; ++j)
            #pragma unroll
            for (int e = 0; e < 4; ++e) acc[i][j][e] = 0.f;

    float xsq[FM];
    #pragma unroll
    for (int i = 0; i < FM; ++i) xsq[i] = 0.f;

    const int nK = K / 32;
    stage(0, 0);
    if (nK > 1) stage(1, 32);

    for (int t = 0; t < nK; ++t) {
        const int cur = t % 3;

        if (t < nK - 1) asm volatile("s_waitcnt vmcnt(%0)" :: "i"(LPT) : "memory");
        else            asm volatile("s_waitcnt vmcnt(0)" ::: "memory");
        asm volatile("s_barrier" ::: "memory");
        __builtin_amdgcn_sched_barrier(0);

        if (t + 2 < nK) stage((t + 2) % 3, (t + 2) * 32);

        bf16x8 af[FM], bfm[FN];
        #pragma unroll
        for (int i = 0; i < FM; ++i)
            af[i] = *(const bf16x8*)&Al[cur * BM * 32 + (wm0 + 16 * i + l15) * 32 + 8 * q];
        #pragma unroll
        for (int j = 0; j < FN; ++j)
            bfm[j] = *(const bf16x8*)&Bl[cur * BN * 32 + (wn0 + 16 * j + l15) * 32 + 8 * q];

        if constexpr (EPI == 6) {
            #pragma unroll
            for (int i = 0; i < FM; ++i)
                #pragma unroll
                for (int e = 0; e < 8; ++e) {
                    float f = (float)af[i][e];
                    xsq[i] = fmaf(f, f, xsq[i]);
                }
        }

        __builtin_amdgcn_s_setprio(1);
        #pragma unroll
        for (int i = 0; i < FM; ++i)
            #pragma unroll
            for (int j = 0; j < FN; ++j)
                acc[i][j] = __builtin_amdgcn_mfma_f32_16x16x32_bf16(af[i], bfm[j], acc[i][j], 0, 0, 0);
        __builtin_amdgcn_s_setprio(0);
    }

    int rowB[FM];
    #pragma unroll
    for (int i = 0; i < FM; ++i) rowB[i] = m0 + wm0 + 16 * i + 4 * q;
    const int colBase = n0 + wn0;

    if constexpr (EPI == 2) {
        bf16_t* O = (bf16_t*)Cg + (size_t)bz * (size_t)cStride;
        #pragma unroll
        for (int j = 0; j < FN; ++j) {
            int col = colBase + 16 * j + l15;
            float a = p0[col], b = p1[col];
            #pragma unroll
            for (int i = 0; i < FM; ++i) {
                int rb = rowB[i];
                #pragma unroll
                for (int e = 0; e < 4; ++e) {
                    float v = fmaxf(fmaf(acc[i][j][e], a, b), 0.f);
                    O[(size_t)(rb + e) * ldC + col] = (bf16_t)v;
                }
            }
        }
    } else if constexpr (EPI == 3) {
        // LDS-bounce the 128x128 bf16 shortcut tile, then epilogue reads LDS.
        float* O = (float*)Cg + (size_t)bz * (size_t)cStride;
        const bf16_t* scg = (const bf16_t*)shortcut + (size_t)bz * (size_t)sStride;
        bf16_t* SP = SH;                       // [128][132]
        float cB = scal[0];
        __syncthreads();
        {
            int row = tid >> 1, h = tid & 1;
            #pragma unroll
            for (int u = 0; u < 8; ++u)
                *(bf16x8*)&SP[row * 132 + h * 64 + u * 8] =
                    *(const bf16x8*)&scg[(size_t)(m0 + row) * ldC + n0 + h * 64 + u * 8];
        }
        __syncthreads();
        #pragma unroll
        for (int i = 0; i < FM; ++i) {
            int rl = wm0 + 16 * i + 4 * q;
            #pragma unroll
            for (int e = 0; e < 4; ++e) {
                int row = m0 + rl + e;
                float a = p0[row], b = p1[row];
                #pragma unroll
                for (int j = 0; j < FN; ++j) {
                    int cl = wn0 + 16 * j + l15;
                    float v = fmaf(acc[i][j][e], a, b)
                            + cB * (float)SP[(rl + e) * 132 + cl];
                    O[(size_t)row * ldC + n0 + cl] = fmaxf(v, 0.f);
                }
            }
        }
    } else if constexpr (EPI == 5) {
        float* O = (float*)Cg + (size_t)bz * (size_t)cStride;
        #pragma unroll
        for (int i = 0; i < FM; ++i) {
            int rb = rowB[i];
            #pragma unroll
            for (int j = 0; j < FN; ++j) {
                int col = colBase + 16 * j + l15;
                *(f32x4*)&O[(size_t)col * ldC + rb] = acc[i][j];
            }
        }
    } else if constexpr (EPI == 6) {
        bf16_t* Cc = (bf16_t*)Cg  + (size_t)bz * (size_t)cStride;
        bf16_t* Ct = (bf16_t*)C2g + (size_t)(bz >> 1) * (size_t)c2Stride;
        const int hoff = (bz & 1) * 64;
        const bool doCt = (C2g != nullptr);
        float xs[FM];
        #pragma unroll
        for (int i = 0; i < FM; ++i) {
            float s2 = xsq[i];
            s2 += __shfl_xor(s2, 16);
            s2 += __shfl_xor(s2, 32);
            xs[i] = s2;
        }
        float di[FN];
        #pragma unroll
        for (int j = 0; j < FN; ++j) di[j] = dl[16 * j + l15];
        #pragma unroll
        for (int i = 0; i < FM; ++i) {
            int rb = rowB[i];
            bf16x4 tj[FN];
            #pragma unroll
            for (int e = 0; e < 4; ++e) {
                float s2row = __shfl(xs[i], 4 * q + e);
                float xi = 1.0f / (10.0f * fmaxf(sqrtf(s2row), HEPS));
                float v[FN];
                float mx = -1e30f;
                #pragma unroll
                for (int j = 0; j < FN; ++j) {
                    v[j] = acc[i][j][e] * di[j] * xi;
                    mx = fmaxf(mx, v[j]);
                }
                mx = fmaxf(mx, __shfl_xor(mx, 1));
                mx = fmaxf(mx, __shfl_xor(mx, 2));
                mx = fmaxf(mx, __shfl_xor(mx, 4));
                mx = fmaxf(mx, __shfl_xor(mx, 8));
                float sm = 0.f;
                #pragma unroll
                for (int j = 0; j < FN; ++j) { v[j] = __expf(v[j] - mx); sm += v[j]; }
                sm += __shfl_xor(sm, 1);
                sm += __shfl_xor(sm, 2);
                sm += __shfl_xor(sm, 4);
                sm += __shfl_xor(sm, 8);
                float rs = 1.0f / sm;
                #pragma unroll
                for (int j = 0; j < FN; ++j) {
                    float p = v[j] * rs;
                    tj[j][e] = (bf16_t)p;
                    if (doCt) Ct[(size_t)(rb + e) * 128 + hoff + 16 * j + l15] = (bf16_t)p;
                }
            }
            #pragma unroll
            for (int j = 0; j < FN; ++j)
                *(bf16x4*)&Cc[(size_t)(16 * j + l15) * ldC + rb] = tj[j];
        }
    } else if constexpr (EPI == 7) {
        bf16_t* O = (bf16_t*)Cg + (size_t)(bz >> 1) * (size_t)cStride;
        const int hoff = (bz & 1) * 64;
        #pragma unroll
        for (int j = 0; j < FN; ++j) {
            int col = colBase + 16 * j + l15;
            float di = p0[bz * 64 + col];
            #pragma unroll
            for (int i = 0; i < FM; ++i) {
                int rb = rowB[i];
                #pragma unroll
                for (int e = 0; e < 4; ++e)
                    O[(size_t)(rb + e) * 128 + hoff + col] = (bf16_t)(acc[i][j][e] * di);
            }
        }
    } else if constexpr (EPI == 9) {
        // rows = do, cols = n. Single output: Xt[b][n][do] via bf16x4 (do-contig).
        bf16_t* O = (bf16_t*)Cg + (size_t)bz * (size_t)cStride;
        #pragma unroll
        for (int j = 0; j < FN; ++j) {
            int col = colBase + 16 * j + l15;     // n
            #pragma unroll
            for (int i = 0; i < FM; ++i) {
                int rb = rowB[i];                 // do
                bf16x4 t;
                #pragma unroll
                for (int e = 0; e < 4; ++e)
                    t[e] = (bf16_t)fmaxf(acc[i][j][e] + p0[rb + e], 0.f);
                *(bf16x4*)&O[(size_t)col * ldC + rb] = t;
            }
        }
    }
}

// ---------------- host launcher ----------------

extern "C" void kernel_launch(void* const* d_in, const int* in_sizes, int n_in,
                              void* d_out, int out_size, void* d_ws, size_t ws_size,
                              hipStream_t stream) {
    const float* z        = (const float*)d_in[0];
    const float* lower_w  = (const float*)d_in[1];
    const float* lower_b  = (const float*)d_in[2];
    const float* Dinit_s  = (const float*)d_in[3];
    const float* Dinit_c  = (const float*)d_in[4];
    const float* cheese_w = (const float*)d_in[5];
    const float* ch_gamma = (const float*)d_in[6];
    const float* ch_beta  = (const float*)d_in[7];
    const float* ch_mean  = (const float*)d_in[8];
    const float* ch_var   = (const float*)d_in[9];
    const float* upper_w  = (const float*)d_in[10];
    const float* upper_b  = (const float*)d_in[11];
    const float* h_gamma  = (const float*)d_in[12];
    const float* h_beta   = (const float*)d_in[13];
    const float* h_mean   = (const float*)d_in[14];
    const float* h_var    = (const float*)d_in[15];
    const float* coef_ham = (const float*)d_in[16];
    const float* coef_sc  = (const float*)d_in[17];

    char* ws = (char*)d_ws;
    size_t off = 0;
    auto alloc = [&](size_t bytes) -> void* {
        void* p = ws + off;
        off += (bytes + 255) & ~(size_t)255;
        return p;
    };

    bf16_t* Wl   = (bf16_t*)alloc((size_t)1024 * 512 * 2);
    bf16_t* Wc   = (bf16_t*)alloc((size_t)1024 * 1024 * 2);
    bf16_t* Wu   = (bf16_t*)alloc((size_t)512 * 1024 * 2);
    float*  chA  = (float*) alloc(1024 * 4);
    float*  chB  = (float*) alloc(1024 * 4);
    float*  hA2  = (float*) alloc(512 * 4);
    float*  hB2  = (float*) alloc(512 * 4);
    float*  dinv = (float*) alloc(1024 * 4);
    bf16_t* Xbf  = (bf16_t*)alloc((size_t)8 * 1024 * 4096 * 2);   // X; later Ycht
    bf16_t* Xt   = (bf16_t*)alloc((size_t)8 * 4096 * 1024 * 2);   // Xt
    bf16_t* Zt   = (bf16_t*)alloc((size_t)8 * 4096 * 512 * 2);
    bf16_t* zb   = (bf16_t*)alloc((size_t)8 * 512 * 4096 * 2);    // bf16 copy of z
    bf16_t* Cb   = (bf16_t*)alloc((size_t)16 * 64 * 4096 * 2);
    bf16_t* Ct2  = (bf16_t*)alloc((size_t)8 * 4096 * 128 * 2);
    float*  P    = (float*) alloc((size_t)128 * 64 * 512 * 4);    // split-K=8
    bf16_t* Dta  = (bf16_t*)alloc((size_t)16 * 64 * 512 * 2);
    bf16_t* Dtb  = (bf16_t*)alloc((size_t)16 * 64 * 512 * 2);
    bf16_t* Eb   = (bf16_t*)alloc((size_t)8 * 1024 * 128 * 2);
    bf16_t* Ycht = Xbf;

    dim3 blk(256);

    setup_k<<<10244, blk, 0, stream>>>(lower_w, Wl, cheese_w, Wc, upper_w, Wu,
                                       Dinit_s, Dinit_c, Dta,
                                       ch_gamma, ch_beta, ch_mean, ch_var,
                                       h_gamma, h_beta, h_mean, h_var,
                                       upper_b, coef_ham, chA, chB, hA2, hB2);
    tz_k<<<dim3(64, 8, 8), blk, 0, stream>>>(z, Zt, zb);

    // G1'': Xt[b][n][do] = relu(Wl @ Zt^T + bias), m=do, transposed bf16x4 store (Xt only)
    g2<128, 128, 2, 2, 9, 0><<<dim3(32, 8, 8), blk, 0, stream>>>(
        Wl, Zt, (void*)Xt, nullptr, 1024, 4096, 512,
        512, 512, 1024,
        0L, (long)4096 * 512, (long)4096 * 1024, 0L,
        lower_b, nullptr, nullptr, nullptr, 0L);

    // X = transpose(Xt) via LDS tiles
    xp_k<<<dim3(64, 16, 8), blk, 0, stream>>>(Xt, Xbf);

    dnorm_k<<<256, blk, 0, stream>>>(Dta, dinv);

    bf16_t* cur = Dta;
    bf16_t* nxt = Dtb;
    for (int t = 0; t < 3; ++t) {
        // S^T + softmax: BM=128, 4x1 waves -> 512 blocks
        g2<128, 64, 4, 1, 6, 0><<<dim3(1, 32, 16), blk, 0, stream>>>(
            Xt, cur, (void*)Cb, (t == 2) ? (void*)Ct2 : nullptr, 4096, 64, 512,
            1024, 512, 4096,
            (long)4096 * 1024, (long)64 * 512, (long)64 * 4096, (long)4096 * 128,
            dinv, nullptr, nullptr, nullptr, 0L);
        // XCt split-K=8, BM=64 -> 1024 blocks: P[bs*8+kc][r][d]
        g2<64, 64, 2, 2, 5, 0><<<dim3(1, 8, 128), blk, 0, stream>>>(
            Xbf, Cb, (void*)P, nullptr, 512, 64, 512,
            4096, 4096, 512,
            (long)512 * 4096, (long)64 * 4096, (long)64 * 512, 0L,
            nullptr, nullptr, nullptr, nullptr, 0L);
        reduce_k<<<1024, dim3(64), 0, stream>>>(P, nxt, dinv);
        bf16_t* tmp = cur; cur = nxt; nxt = tmp;
    }

    // E[b][c][128] = concat_s( Wc[:, s*512:]*D2_s )
    g2<128, 64, 2, 2, 7, 0><<<dim3(1, 8, 16), blk, 0, stream>>>(
        Wc, cur, (void*)Eb, nullptr, 1024, 64, 512,
        1024, 512, 128,
        0L, (long)64 * 512, (long)1024 * 128, 0L,
        dinv, nullptr, nullptr, nullptr, 0L);

    // cheese': Ycht[b][n][c] = relu(bn(Ct2[n][:] @ E[c][:]^T))
    g2<128, 128, 2, 2, 2, 0><<<dim3(8, 32, 8), blk, 0, stream>>>(
        Ct2, Eb, (void*)Ycht, nullptr, 4096, 1024, 128,
        128, 128, 1024,
        (long)4096 * 128, (long)1024 * 128, (long)4096 * 1024, 0L,
        chA, chB, nullptr, nullptr, 0L);

    // upper: out = relu(hA2*(Wu @ Ych) + hB2 + cB*zb), LDS-bounced shortcut
    g2<128, 128, 2, 2, 3, 1><<<dim3(32, 4, 8), blk, 0, stream>>>(
        Wu, Ycht, d_out, nullptr, 512, 4096, 1024,
        1024, 1024, 4096,
        0L, (long)4096 * 1024, (long)512 * 4096, 0L,
        hA2, hB2, coef_sc, zb, (long)512 * 4096);

    (void)in_sizes; (void)n_in; (void)out_size; (void)ws_size;
}

// Round 16
// 308.067 us; speedup vs baseline: 1.0792x; 1.0792x over previous
//
#include <hip/hip_runtime.h>
#include <hip/hip_bf16.h>

typedef __bf16 bf16_t;
typedef __bf16 bf16x4 __attribute__((ext_vector_type(4)));
typedef __bf16 bf16x8 __attribute__((ext_vector_type(8)));
typedef float  f32x4  __attribute__((ext_vector_type(4)));

#define HEPS 1e-6f

__device__ __forceinline__ void gload16(const bf16_t* g, bf16_t* l) {
    __builtin_amdgcn_global_load_lds(
        (const __attribute__((address_space(1))) unsigned int*)(g),
        (__attribute__((address_space(3))) unsigned int*)(l),
        16, 0, 0);
}

// ---------------- setup: weight cvt + Dinit transpose + BN folding, one launch ----------
__global__ void setup_k(const float* __restrict__ wl, bf16_t* __restrict__ dwl,
                        const float* __restrict__ wc, bf16_t* __restrict__ dwc,
                        const float* __restrict__ wu, bf16_t* __restrict__ dwu,
                        const float* __restrict__ Ds, const float* __restrict__ Dc,
                        bf16_t* __restrict__ Dt,
                        const float* __restrict__ chg, const float* __restrict__ chb,
                        const float* __restrict__ chm, const float* __restrict__ chv,
                        const float* __restrict__ hg, const float* __restrict__ hb,
                        const float* __restrict__ hm, const float* __restrict__ hv,
                        const float* __restrict__ ub, const float* __restrict__ cham,
                        float* __restrict__ chA, float* __restrict__ chB,
                        float* __restrict__ hA2, float* __restrict__ hB2) {
    int bid = blockIdx.x;
    int tid = threadIdx.x;
    if (bid < 8192) {
        int i = bid * 256 + tid;
        if (i < 524288) dwl[i] = (bf16_t)wl[i];
        else if (i < 1572864) { int k = i - 524288; dwc[k] = (bf16_t)wc[k]; }
        else { int k = i - 1572864; dwu[k] = (bf16_t)wu[k]; }
    } else if (bid < 10240) {
        int b2 = bid - 8192;
        int bs = b2 >> 7;
        int idx = (b2 & 127) * 256 + tid;
        int b = bs >> 1;
        const float* src = ((bs & 1) ? Dc : Ds) + (size_t)b * 512 * 64;
        int r = idx & 63, d = idx >> 6;
        Dt[(size_t)bs * 64 * 512 + (size_t)r * 512 + d] = (bf16_t)src[d * 64 + r];
    } else {
        int i = (bid - 10240) * 256 + tid;
        if (i < 1024) {
            float inv = chg[i] * rsqrtf(chv[i] + 1e-5f);
            chA[i] = inv;
            chB[i] = chb[i] - chm[i] * inv;
        }
        if (i < 512) {
            float inv = hg[i] * rsqrtf(hv[i] + 1e-5f);
            float cA = cham[0];
            hA2[i] = cA * inv;
            hB2[i] = cA * (fmaf(ub[i], inv, hb[i]) - hm[i] * inv);
        }
    }
}

// z [b][512][4096] fp32 -> Zt [b][4096][512] bf16, plus zb = bf16 copy of z
__global__ void tz_k(const float* __restrict__ z, bf16_t* __restrict__ Zt,
                     bf16_t* __restrict__ zb) {
    __shared__ bf16_t t[64][68];
    int b = blockIdx.z, kt = blockIdx.y, nt = blockIdx.x;
    const size_t boff = ((size_t)b * 512 + kt * 64) * 4096 + nt * 64;
    const float* src = z + boff;
    bf16_t* zbo = zb + boff;
    int tid = threadIdx.x;
    int kr = tid >> 4;
    int nc = (tid & 15) * 4;
    #pragma unroll
    for (int it = 0; it < 4; ++it) {
        int k = kr + it * 16;
        float4 v = *(const float4*)&src[(size_t)k * 4096 + nc];
        bf16x4 o;
        o[0] = (bf16_t)v.x; o[1] = (bf16_t)v.y; o[2] = (bf16_t)v.z; o[3] = (bf16_t)v.w;
        t[nc + 0][k] = o[0]; t[nc + 1][k] = o[1];
        t[nc + 2][k] = o[2]; t[nc + 3][k] = o[3];
        *(bf16x4*)&zbo[(size_t)k * 4096 + nc] = o;
    }
    __syncthreads();
    bf16_t* dst = Zt + ((size_t)b * 4096 + nt * 64) * 512 + kt * 64;
    int nr = tid >> 4;
    int kc = (tid & 15) * 4;
    #pragma unroll
    for (int it = 0; it < 4; ++it) {
        int n = nr + it * 16;
        bf16x4 o;
        #pragma unroll
        for (int c = 0; c < 4; ++c) o[c] = t[n][kc + c];
        *(bf16x4*)&dst[(size_t)n * 512 + kc] = o;
    }
}

__global__ void dnorm_k(const bf16_t* __restrict__ Dt, float* __restrict__ dinv) {
    int gw = (blockIdx.x * 256 + threadIdx.x) >> 6;
    int lane = threadIdx.x & 63;
    bf16x8 v = *(const bf16x8*)(Dt + (size_t)gw * 512 + lane * 8);
    float s = 0.f;
    #pragma unroll
    for (int e = 0; e < 8; ++e) { float f = (float)v[e]; s += f * f; }
    #pragma unroll
    for (int off = 32; off > 0; off >>= 1) s += __shfl_xor(s, off);
    if (lane == 0) dinv[gw] = 1.0f / fmaxf(sqrtf(s), HEPS);
}

// sum 8 split-K partials P[bs*8+kc][r][d] -> Dt bf16, plus dinv of summed rows
// 256 threads = 4 (bs,r) rows per block
__global__ void reduce_k(const float* __restrict__ P, bf16_t* __restrict__ Dt,
                         float* __restrict__ dinv) {
    int bsr = blockIdx.x * 4 + (threadIdx.x >> 6);
    int bs = bsr >> 6, r = bsr & 63;
    int lane = threadIdx.x & 63;
    const float* base = P + ((size_t)(bs * 8) * 64 + r) * 512 + lane * 8;
    float s[8] = {0.f, 0.f, 0.f, 0.f, 0.f, 0.f, 0.f, 0.f};
    #pragma unroll
    for (int kc = 0; kc < 8; ++kc) {
        const float* p = base + (size_t)kc * 64 * 512;
        float4 u = *(const float4*)p;
        float4 w = *(const float4*)(p + 4);
        s[0] += u.x; s[1] += u.y; s[2] += u.z; s[3] += u.w;
        s[4] += w.x; s[5] += w.y; s[6] += w.z; s[7] += w.w;
    }
    bf16x8 o;
    float sq = 0.f;
    #pragma unroll
    for (int e = 0; e < 8; ++e) { sq += s[e] * s[e]; o[e] = (bf16_t)s[e]; }
    *(bf16x8*)&Dt[(size_t)bsr * 512 + lane * 8] = o;
    #pragma unroll
    for (int off = 32; off > 0; off >>= 1) sq += __shfl_xor(sq, off);
    if (lane == 0) dinv[bsr] = 1.0f / fmaxf(sqrtf(sq), HEPS);
}

// ---------------- MFMA GEMM: 3-buffer, counted vmcnt, SINGLE barrier per K-step --------
// EPI 2: cheese' (col a*x+b, relu, bf16)
// EPI 3: upper (row a*x+b + cB*bf16-shortcut via LDS-bounced tile, relu, fp32)
// EPI 5: XCt split-K=8 partial (transposed fp32)
// EPI 6: S^T + fused row softmax (WAVES_N must be 1)
// EPI 7: E (scale col by dinv, concat store)
// EPI 8: G1' (col bias + relu, dual store: Xt scalar + X via bf16x4 col-store)
template<int BM, int BN, int WAVES_M, int WAVES_N, int EPI, int ORDER>
__launch_bounds__(256)
__global__ void g2(const bf16_t* __restrict__ Ag, const bf16_t* __restrict__ Bg,
                   void* __restrict__ Cg, void* __restrict__ C2g,
                   const int M, const int N, const int K,
                   const int ldA, const int ldB, const int ldC,
                   const long aStride, const long bStride,
                   const long cStride, const long c2Stride,
                   const float* __restrict__ p0, const float* __restrict__ p1,
                   const float* __restrict__ scal,
                   const void* __restrict__ shortcut, const long sStride)
{
    constexpr int WM = BM / WAVES_M, WN = BN / WAVES_N;
    constexpr int FM = WM / 16, FN = WN / 16;
    constexpr int ASEG = BM / 64, BSEG = BN / 64;
    constexpr int LPT = ASEG + BSEG;

    __shared__ __align__(64) bf16_t SH[3 * (BM + BN) * 32];
    __shared__ float dl[64];
    bf16_t* Al = SH;
    bf16_t* Bl = SH + 3 * BM * 32;

    const int tid = threadIdx.x;
    const int wave = tid >> 6, lane = tid & 63;
    const int l15 = lane & 15, q = lane >> 4;
    const int lrow = lane >> 2, lcol = (lane & 3) * 8;

    // ---- XCD-chunked bijective remap (m204) ----
    const int gx = gridDim.x, gy = gridDim.y;
    const int per = gx * gy;
    const int nwg = per * gridDim.z;
    const int g = blockIdx.z * per + blockIdx.y * gx + blockIdx.x;
    const int qq = nwg >> 3, rr = nwg & 7;
    const int xcd = g & 7, jj = g >> 3;
    const int w = (xcd < rr ? xcd * (qq + 1) : rr * (qq + 1) + (xcd - rr) * qq) + jj;
    const int bz = w / per;
    const int rem = w - bz * per;
    int bx, by;
    if constexpr (ORDER == 0) { by = rem / gx; bx = rem - by * gx; }
    else                      { bx = rem / gy; by = rem - bx * gy; }

    int bs = bz, exA = 0, exB = 0;
    if constexpr (EPI == 5) { bs = bz >> 3; exA = exB = (bz & 7) * 512; }
    if constexpr (EPI == 7) { exA = (bz & 1) * 512; }

    const int n0 = bx * BN;
    const int m0 = by * BM;
    const int wm0 = (wave / WAVES_N) * WM;
    const int wn0 = (wave % WAVES_N) * WN;

    const bf16_t* Ab;
    const bf16_t* Bb;
    if constexpr (EPI == 6) {
        Ab = Ag + (size_t)(bz >> 1) * (size_t)aStride + (size_t)(bz & 1) * 512;
        Bb = Bg + (size_t)bz * (size_t)bStride;
    } else {
        Ab = Ag + (size_t)bs * (size_t)aStride + exA;
        Bb = Bg + (size_t)bs * (size_t)bStride + exB;
    }

    if constexpr (EPI == 6) { if (tid < 64) dl[tid] = p0[bz * 64 + tid]; }

    auto stage = [&](int buf, int k0) {
        #pragma unroll
        for (int t = 0; t < ASEG; ++t) {
            int seg = wave * ASEG + t;
            gload16(Ab + (size_t)(m0 + seg * 16 + lrow) * ldA + k0 + lcol,
                    &Al[buf * BM * 32 + seg * 512]);
        }
        #pragma unroll
        for (int t = 0; t < BSEG; ++t) {
            int seg = wave * BSEG + t;
            gload16(Bb + (size_t)(n0 + seg * 16 + lrow) * ldB + k0 + lcol,
                    &Bl[buf * BN * 32 + seg * 512]);
        }
    };

    f32x4 acc[FM][FN];
    #pragma unroll
    for (int i = 0; i < FM; ++i)
        #pragma unroll
        for (int j = 0; j < FN; ++j)
            #pragma unroll
            for (int e = 0; e < 4; ++e) acc[i][j][e] = 0.f;

    float xsq[FM];
    #pragma unroll
    for (int i = 0; i < FM; ++i) xsq[i] = 0.f;

    const int nK = K / 32;
    stage(0, 0);
    if (nK > 1) stage(1, 32);

    for (int t = 0; t < nK; ++t) {
        const int cur = t % 3;

        if (t < nK - 1) asm volatile("s_waitcnt vmcnt(%0)" :: "i"(LPT) : "memory");
        else            asm volatile("s_waitcnt vmcnt(0)" ::: "memory");
        asm volatile("s_barrier" ::: "memory");
        __builtin_amdgcn_sched_barrier(0);

        if (t + 2 < nK) stage((t + 2) % 3, (t + 2) * 32);

        bf16x8 af[FM], bfm[FN];
        #pragma unroll
        for (int i = 0; i < FM; ++i)
            af[i] = *(const bf16x8*)&Al[cur * BM * 32 + (wm0 + 16 * i + l15) * 32 + 8 * q];
        #pragma unroll
        for (int j = 0; j < FN; ++j)
            bfm[j] = *(const bf16x8*)&Bl[cur * BN * 32 + (wn0 + 16 * j + l15) * 32 + 8 * q];

        if constexpr (EPI == 6) {
            #pragma unroll
            for (int i = 0; i < FM; ++i)
                #pragma unroll
                for (int e = 0; e < 8; ++e) {
                    float f = (float)af[i][e];
                    xsq[i] = fmaf(f, f, xsq[i]);
                }
        }

        __builtin_amdgcn_s_setprio(1);
        #pragma unroll
        for (int i = 0; i < FM; ++i)
            #pragma unroll
            for (int j = 0; j < FN; ++j)
                acc[i][j] = __builtin_amdgcn_mfma_f32_16x16x32_bf16(af[i], bfm[j], acc[i][j], 0, 0, 0);
        __builtin_amdgcn_s_setprio(0);
    }

    int rowB[FM];
    #pragma unroll
    for (int i = 0; i < FM; ++i) rowB[i] = m0 + wm0 + 16 * i + 4 * q;
    const int colBase = n0 + wn0;

    if constexpr (EPI == 2) {
        bf16_t* O = (bf16_t*)Cg + (size_t)bz * (size_t)cStride;
        #pragma unroll
        for (int j = 0; j < FN; ++j) {
            int col = colBase + 16 * j + l15;
            float a = p0[col], b = p1[col];
            #pragma unroll
            for (int i = 0; i < FM; ++i) {
                int rb = rowB[i];
                #pragma unroll
                for (int e = 0; e < 4; ++e) {
                    float v = fmaxf(fmaf(acc[i][j][e], a, b), 0.f);
                    O[(size_t)(rb + e) * ldC + col] = (bf16_t)v;
                }
            }
        }
    } else if constexpr (EPI == 3) {
        // LDS-bounce the 128x128 bf16 shortcut tile, then epilogue reads LDS.
        float* O = (float*)Cg + (size_t)bz * (size_t)cStride;
        const bf16_t* scg = (const bf16_t*)shortcut + (size_t)bz * (size_t)sStride;
        bf16_t* SP = SH;                       // [128][132]
        float cB = scal[0];
        __syncthreads();
        {
            int row = tid >> 1, h = tid & 1;
            #pragma unroll
            for (int u = 0; u < 8; ++u)
                *(bf16x8*)&SP[row * 132 + h * 64 + u * 8] =
                    *(const bf16x8*)&scg[(size_t)(m0 + row) * ldC + n0 + h * 64 + u * 8];
        }
        __syncthreads();
        #pragma unroll
        for (int i = 0; i < FM; ++i) {
            int rl = wm0 + 16 * i + 4 * q;
            #pragma unroll
            for (int e = 0; e < 4; ++e) {
                int row = m0 + rl + e;
                float a = p0[row], b = p1[row];
                #pragma unroll
                for (int j = 0; j < FN; ++j) {
                    int cl = wn0 + 16 * j + l15;
                    float v = fmaf(acc[i][j][e], a, b)
                            + cB * (float)SP[(rl + e) * 132 + cl];
                    O[(size_t)row * ldC + n0 + cl] = fmaxf(v, 0.f);
                }
            }
        }
    } else if constexpr (EPI == 5) {
        float* O = (float*)Cg + (size_t)bz * (size_t)cStride;
        #pragma unroll
        for (int i = 0; i < FM; ++i) {
            int rb = rowB[i];
            #pragma unroll
            for (int j = 0; j < FN; ++j) {
                int col = colBase + 16 * j + l15;
                *(f32x4*)&O[(size_t)col * ldC + rb] = acc[i][j];
            }
        }
    } else if constexpr (EPI == 6) {
        bf16_t* Cc = (bf16_t*)Cg  + (size_t)bz * (size_t)cStride;
        bf16_t* Ct = (bf16_t*)C2g + (size_t)(bz >> 1) * (size_t)c2Stride;
        const int hoff = (bz & 1) * 64;
        const bool doCt = (C2g != nullptr);
        float xs[FM];
        #pragma unroll
        for (int i = 0; i < FM; ++i) {
            float s2 = xsq[i];
            s2 += __shfl_xor(s2, 16);
            s2 += __shfl_xor(s2, 32);
            xs[i] = s2;
        }
        float di[FN];
        #pragma unroll
        for (int j = 0; j < FN; ++j) di[j] = dl[16 * j + l15];
        #pragma unroll
        for (int i = 0; i < FM; ++i) {
            int rb = rowB[i];
            bf16x4 tj[FN];
            #pragma unroll
            for (int e = 0; e < 4; ++e) {
                float s2row = __shfl(xs[i], 4 * q + e);
                float xi = 1.0f / (10.0f * fmaxf(sqrtf(s2row), HEPS));
                float v[FN];
                float mx = -1e30f;
                #pragma unroll
                for (int j = 0; j < FN; ++j) {
                    v[j] = acc[i][j][e] * di[j] * xi;
                    mx = fmaxf(mx, v[j]);
                }
                mx = fmaxf(mx, __shfl_xor(mx, 1));
                mx = fmaxf(mx, __shfl_xor(mx, 2));
                mx = fmaxf(mx, __shfl_xor(mx, 4));
                mx = fmaxf(mx, __shfl_xor(mx, 8));
                float sm = 0.f;
                #pragma unroll
                for (int j = 0; j < FN; ++j) { v[j] = __expf(v[j] - mx); sm += v[j]; }
                sm += __shfl_xor(sm, 1);
                sm += __shfl_xor(sm, 2);
                sm += __shfl_xor(sm, 4);
                sm += __shfl_xor(sm, 8);
                float rs = 1.0f / sm;
                #pragma unroll
                for (int j = 0; j < FN; ++j) {
                    float p = v[j] * rs;
                    tj[j][e] = (bf16_t)p;
                    if (doCt) Ct[(size_t)(rb + e) * 128 + hoff + 16 * j + l15] = (bf16_t)p;
                }
            }
            #pragma unroll
            for (int j = 0; j < FN; ++j)
                *(bf16x4*)&Cc[(size_t)(16 * j + l15) * ldC + rb] = tj[j];
        }
    } else if constexpr (EPI == 7) {
        bf16_t* O = (bf16_t*)Cg + (size_t)(bz >> 1) * (size_t)cStride;
        const int hoff = (bz & 1) * 64;
        #pragma unroll
        for (int j = 0; j < FN; ++j) {
            int col = colBase + 16 * j + l15;
            float di = p0[bz * 64 + col];
            #pragma unroll
            for (int i = 0; i < FM; ++i) {
                int rb = rowB[i];
                #pragma unroll
                for (int e = 0; e < 4; ++e)
                    O[(size_t)(rb + e) * 128 + hoff + col] = (bf16_t)(acc[i][j][e] * di);
            }
        }
    } else if constexpr (EPI == 8) {
        // rows = n (4096), cols = do (1024). Xt scalar + X transposed via bf16x4.
        bf16_t* O  = (bf16_t*)Cg  + (size_t)bz * (size_t)cStride;   // Xt [4096][1024]
        bf16_t* O2 = (bf16_t*)C2g + (size_t)bz * (size_t)c2Stride;  // X  [1024][4096]
        #pragma unroll
        for (int j = 0; j < FN; ++j) {
            int col = colBase + 16 * j + l15;
            float bias = p0[col];
            #pragma unroll
            for (int i = 0; i < FM; ++i) {
                int rb = rowB[i];
                bf16x4 t;
                #pragma unroll
                for (int e = 0; e < 4; ++e) {
                    float v = fmaxf(acc[i][j][e] + bias, 0.f);
                    t[e] = (bf16_t)v;
                    O[(size_t)(rb + e) * ldC + col] = t[e];
                }
                *(bf16x4*)&O2[(size_t)col * 4096 + rb] = t;
            }
        }
    }
}

// ---------------- host launcher ----------------

extern "C" void kernel_launch(void* const* d_in, const int* in_sizes, int n_in,
                              void* d_out, int out_size, void* d_ws, size_t ws_size,
                              hipStream_t stream) {
    const float* z        = (const float*)d_in[0];
    const float* lower_w  = (const float*)d_in[1];
    const float* lower_b  = (const float*)d_in[2];
    const float* Dinit_s  = (const float*)d_in[3];
    const float* Dinit_c  = (const float*)d_in[4];
    const float* cheese_w = (const float*)d_in[5];
    const float* ch_gamma = (const float*)d_in[6];
    const float* ch_beta  = (const float*)d_in[7];
    const float* ch_mean  = (const float*)d_in[8];
    const float* ch_var   = (const float*)d_in[9];
    const float* upper_w  = (const float*)d_in[10];
    const float* upper_b  = (const float*)d_in[11];
    const float* h_gamma  = (const float*)d_in[12];
    const float* h_beta   = (const float*)d_in[13];
    const float* h_mean   = (const float*)d_in[14];
    const float* h_var    = (const float*)d_in[15];
    const float* coef_ham = (const float*)d_in[16];
    const float* coef_sc  = (const float*)d_in[17];

    char* ws = (char*)d_ws;
    size_t off = 0;
    auto alloc = [&](size_t bytes) -> void* {
        void* p = ws + off;
        off += (bytes + 255) & ~(size_t)255;
        return p;
    };

    bf16_t* Wl   = (bf16_t*)alloc((size_t)1024 * 512 * 2);
    bf16_t* Wc   = (bf16_t*)alloc((size_t)1024 * 1024 * 2);
    bf16_t* Wu   = (bf16_t*)alloc((size_t)512 * 1024 * 2);
    float*  chA  = (float*) alloc(1024 * 4);
    float*  chB  = (float*) alloc(1024 * 4);
    float*  hA2  = (float*) alloc(512 * 4);
    float*  hB2  = (float*) alloc(512 * 4);
    float*  dinv = (float*) alloc(1024 * 4);
    bf16_t* Xbf  = (bf16_t*)alloc((size_t)8 * 1024 * 4096 * 2);   // X; later Ycht
    bf16_t* Xt   = (bf16_t*)alloc((size_t)8 * 4096 * 1024 * 2);   // Xt
    bf16_t* Zt   = (bf16_t*)alloc((size_t)8 * 4096 * 512 * 2);
    bf16_t* zb   = (bf16_t*)alloc((size_t)8 * 512 * 4096 * 2);    // bf16 copy of z
    bf16_t* Cb   = (bf16_t*)alloc((size_t)16 * 64 * 4096 * 2);
    bf16_t* Ct2  = (bf16_t*)alloc((size_t)8 * 4096 * 128 * 2);
    float*  P    = (float*) alloc((size_t)128 * 64 * 512 * 4);    // split-K=8
    bf16_t* Dta  = (bf16_t*)alloc((size_t)16 * 64 * 512 * 2);
    bf16_t* Dtb  = (bf16_t*)alloc((size_t)16 * 64 * 512 * 2);
    bf16_t* Eb   = (bf16_t*)alloc((size_t)8 * 1024 * 128 * 2);
    bf16_t* Ycht = Xbf;

    dim3 blk(256);

    setup_k<<<10244, blk, 0, stream>>>(lower_w, Wl, cheese_w, Wc, upper_w, Wu,
                                       Dinit_s, Dinit_c, Dta,
                                       ch_gamma, ch_beta, ch_mean, ch_var,
                                       h_gamma, h_beta, h_mean, h_var,
                                       upper_b, coef_ham, chA, chB, hA2, hB2);
    tz_k<<<dim3(64, 8, 8), blk, 0, stream>>>(z, Zt, zb);

    // G1': Xt[b][n][do] = relu(Zt[n][:]·Wl^T + bias); dual store Xt + X
    g2<128, 128, 2, 2, 8, 0><<<dim3(8, 32, 8), blk, 0, stream>>>(
        Zt, Wl, (void*)Xt, (void*)Xbf, 4096, 1024, 512,
        512, 512, 1024,
        (long)4096 * 512, 0L, (long)4096 * 1024, (long)1024 * 4096,
        lower_b, nullptr, nullptr, nullptr, 0L);

    dnorm_k<<<256, blk, 0, stream>>>(Dta, dinv);

    bf16_t* cur = Dta;
    bf16_t* nxt = Dtb;
    for (int t = 0; t < 3; ++t) {
        // S^T + softmax: BM=128, 4x1 waves -> 512 blocks
        g2<128, 64, 4, 1, 6, 0><<<dim3(1, 32, 16), blk, 0, stream>>>(
            Xt, cur, (void*)Cb, (t == 2) ? (void*)Ct2 : nullptr, 4096, 64, 512,
            1024, 512, 4096,
            (long)4096 * 1024, (long)64 * 512, (long)64 * 4096, (long)4096 * 128,
            dinv, nullptr, nullptr, nullptr, 0L);
        // XCt split-K=8, BM=64 -> 1024 blocks: P[bs*8+kc][r][d]
        g2<64, 64, 2, 2, 5, 0><<<dim3(1, 8, 128), blk, 0, stream>>>(
            Xbf, Cb, (void*)P, nullptr, 512, 64, 512,
            4096, 4096, 512,
            (long)512 * 4096, (long)64 * 4096, (long)64 * 512, 0L,
            nullptr, nullptr, nullptr, nullptr, 0L);
        reduce_k<<<256, blk, 0, stream>>>(P, nxt, dinv);
        bf16_t* tmp = cur; cur = nxt; nxt = tmp;
    }

    // E[b][c][128] = concat_s( Wc[:, s*512:]*D2_s )
    g2<128, 64, 2, 2, 7, 0><<<dim3(1, 8, 16), blk, 0, stream>>>(
        Wc, cur, (void*)Eb, nullptr, 1024, 64, 512,
        1024, 512, 128,
        0L, (long)64 * 512, (long)1024 * 128, 0L,
        dinv, nullptr, nullptr, nullptr, 0L);

    // cheese': Ycht[b][n][c] = relu(bn(Ct2[n][:] @ E[c][:]^T))
    g2<128, 128, 2, 2, 2, 0><<<dim3(8, 32, 8), blk, 0, stream>>>(
        Ct2, Eb, (void*)Ycht, nullptr, 4096, 1024, 128,
        128, 128, 1024,
        (long)4096 * 128, (long)1024 * 128, (long)4096 * 1024, 0L,
        chA, chB, nullptr, nullptr, 0L);

    // upper: out = relu(hA2*(Wu @ Ych) + hB2 + cB*zb), LDS-bounced shortcut
    g2<128, 128, 2, 2, 3, 1><<<dim3(32, 4, 8), blk, 0, stream>>>(
        Wu, Ycht, d_out, nullptr, 512, 4096, 1024,
        1024, 1024, 4096,
        0L, (long)4096 * 1024, (long)512 * 4096, 0L,
        hA2, hB2, coef_sc, zb, (long)512 * 4096);

    (void)in_sizes; (void)n_in; (void)out_size; (void)ws_size;
}